// Round 8
// baseline (42.749 us; speedup 1.0000x reference)
//
#include <hip/hip_runtime.h>
#include <math.h>

#define B_ 32
#define P_ 1000
#define T_ 16
#define D_ 78
#define O_ 72
#define NXB 16            // p-chunks of 64
#define BIGC 100000000.0f

// ---------------- K1: dist & liou + per-p scalars + per-block partial maxes ----------------
// (unchanged from round 7 — verified)
__global__ __launch_bounds__(1024, 8) void k1(
        const float* __restrict__ preds, const float* __restrict__ targets,
        const int* __restrict__ imgw_p, const int* __restrict__ imgh_p,
        float* __restrict__ dist, float* __restrict__ liou,
        float4* __restrict__ scal4, float* __restrict__ pths,
        float* __restrict__ pmax) {
    __shared__ float pred_s[64 * 81];
    __shared__ float2 tomg[T_ * O_];
    __shared__ float Spart[T_][4][64];
    __shared__ float wmax[16][3];
    __shared__ float cnt_s[T_], clen_s[T_], ts0_s[T_], ts1_s[T_], tth_s[T_];

    const int b = blockIdx.y, bx = blockIdx.x;
    const int p0 = bx * 64;
    const int rows = min(64, P_ - p0);
    const int tid = threadIdx.x;
    const float w = (float)(imgw_p[0] - 1);
    const float h = (float)(imgh_p[0] - 1);
    const float imgwf = (float)imgw_p[0];

    {
        const float4* gbase = (const float4*)(preds + ((size_t)b * P_ + p0) * D_);
        const int n4 = rows * D_ / 4;
        for (int i = tid; i < n4; i += 1024) {
            float4 v = gbase[i];
            int base = i * 4;
            int r = base / D_, c = base - r * D_;
#pragma unroll
            for (int k = 0; k < 4; ++k) {
                int cc = c + k, rr = r;
                if (cc >= D_) { cc -= D_; ++rr; }
                float x = (&v.x)[k];
                if (cc >= 6 || cc == 3) x *= w;
                pred_s[rr * 81 + cc] = x;
            }
        }
    }
    for (int i = tid; i < T_ * O_; i += 1024) {
        int t = i / O_, o = i - t * O_;
        float to = targets[((size_t)b * T_ + t) * D_ + 6 + o] * w;
        float m = (to >= 0.f && to < imgwf) ? 1.f : 0.f;
        tomg[((t >> 2) * O_ + o) * 4 + (t & 3)] = make_float2(to, m);
    }
    __syncthreads();
    if (tid < T_) {
        int t = tid;
        float c = 0.f;
        for (int o = 0; o < O_; ++o) c += tomg[((t >> 2) * O_ + o) * 4 + (t & 3)].y;
        cnt_s[t] = c;
        clen_s[t] = fmaxf(c, 1.f);
        const float* tr = targets + ((size_t)b * T_ + t) * D_;
        ts0_s[t] = tr[2] * h;
        ts1_s[t] = tr[3] * w;
        tth_s[t] = tr[4];
    }
    __syncthreads();

    {
        const int lane = tid & 63;
        const int wv = tid >> 6;
        const int tg = wv & 3;
        const int oq = wv >> 2;
        const float* lrow = pred_s + lane * 81;
        const float4* tg4 = (const float4*)(tomg + (size_t)tg * O_ * 4);
        const int o_lo = oq * 18;
        float S0 = 0.f, S1 = 0.f, S2 = 0.f, S3 = 0.f;
#pragma unroll
        for (int i = 0; i < 18; ++i) {
            int o = o_lo + i;
            float po = lrow[6 + o];
            float4 r0 = tg4[2 * o];
            float4 r1 = tg4[2 * o + 1];
            S0 += r0.y * fabsf(po - r0.x);
            S1 += r0.w * fabsf(po - r0.z);
            S2 += r1.y * fabsf(po - r1.x);
            S3 += r1.w * fabsf(po - r1.z);
        }
        Spart[4 * tg + 0][oq][lane] = S0;
        Spart[4 * tg + 1][oq][lane] = S1;
        Spart[4 * tg + 2][oq][lane] = S2;
        Spart[4 * tg + 3][oq][lane] = S3;
    }
    __syncthreads();

    const int th = tid >> 6, pl = tid & 63;
    const int p = p0 + pl;
    float ldm = 0.f, lsm = 0.f, ltm = 0.f;
    if (pl < rows) {
        float S = ((Spart[th][0][pl] + Spart[th][1][pl]) + Spart[th][2][pl]) + Spart[th][3][pl];
        float dv = S / clen_s[th];
        dist[(size_t)(b * T_ + th) * P_ + p] = dv;
        ldm = dv;
        float c30 = 30.f * cnt_s[th];
        liou[(size_t)(b * T_ + th) * P_ + p] = (c30 - S) / (c30 + S + 1e-9f);
        const float* prow = pred_s + pl * 81;
        float ps0 = prow[2] * h, ps1 = prow[3], pth = prow[4];
        float d0 = ps0 - ts0_s[th], d1 = ps1 - ts1_s[th];
        lsm = sqrtf(d0 * d0 + d1 * d1);
        ltm = fabsf(pth - tth_s[th]) * 180.f;
        if (th == 0) {
            float fc[2];
#pragma unroll
            for (int c = 0; c < 2; ++c) {
                float x = prow[c];
                float pc = 1.f / (1.f + expf(-x));
                float neg = -logf(1.f - pc + 1e-12f) * 0.75f * pc * pc;
                float pos = -logf(pc + 1e-12f) * 0.25f * (1.f - pc) * (1.f - pc);
                fc[c] = pos - neg;
            }
            scal4[(size_t)b * P_ + p] = make_float4(fc[0], fc[1], ps0, ps1);
            pths[(size_t)b * P_ + p] = pth;
        }
    }

    for (int off = 32; off; off >>= 1) {
        ldm = fmaxf(ldm, __shfl_xor(ldm, off, 64));
        lsm = fmaxf(lsm, __shfl_xor(lsm, off, 64));
        ltm = fmaxf(ltm, __shfl_xor(ltm, off, 64));
    }
    if (pl == 0) { wmax[th][0] = ldm; wmax[th][1] = lsm; wmax[th][2] = ltm; }
    __syncthreads();
    if (tid == 0) {
        float m0 = 0.f, m1 = 0.f, m2 = 0.f;
#pragma unroll
        for (int i = 0; i < 16; ++i) {
            m0 = fmaxf(m0, wmax[i][0]);
            m1 = fmaxf(m1, wmax[i][1]);
            m2 = fmaxf(m2, wmax[i][2]);
        }
        float* q = pmax + (size_t)(b * NXB + bx) * 3;
        q[0] = m0; q[1] = m1; q[2] = m2;
    }
}

// ---------------- K2 (fused, array-free): one block per batch ----------------
// Phase 0 (thread = p): cost for all 16 t -> LDS; liou row -> LDS.
// Phase 1 (wave = t): 8 top-4 rounds re-scanning LDS rows; per-lane scalar
//   deact bitmask (no register arrays anywhere -> nothing can spill to scratch).
// Phase 2 (thread = p): membership + conflict resolution + output.
__global__ __launch_bounds__(1024) void k2(
        const float* __restrict__ targets, const int* __restrict__ masks,
        const int* __restrict__ imgw_p, const int* __restrict__ imgh_p,
        const float* __restrict__ dist, const float* __restrict__ liou,
        const float4* __restrict__ scal4, const float* __restrict__ pths,
        const float* __restrict__ pmax,
        int* __restrict__ out) {
    __shared__ float costL[T_][1024];   // 64 KB (padded, sentinel +INF)
    __shared__ float liouL[T_][1024];   // 64 KB (padded, sentinel -INF)
    __shared__ float ts0s[T_], ts1s[T_], tths[T_];
    __shared__ int labs[T_], mks[T_];
    __shared__ int selE[64];

    const int b = blockIdx.x;
    const int tid = threadIdx.x;

    // per-batch maxes from the 16 partials (uniform -> scalar loads)
    float dm = 0.f, sm = 0.f, tm = 0.f;
    for (int i = 0; i < NXB; ++i) {
        const float* q = pmax + (size_t)(b * NXB + i) * 3;
        dm = fmaxf(dm, q[0]); sm = fmaxf(sm, q[1]); tm = fmaxf(tm, q[2]);
    }
    dm = fmaxf(dm, 1e-8f); sm = fmaxf(sm, 1e-8f); tm = fmaxf(tm, 1e-8f);

    const float w = (float)(imgw_p[0] - 1);
    const float h = (float)(imgh_p[0] - 1);
    if (tid < T_) {
        const float* tr = targets + (size_t)(b * T_ + tid) * D_;
        ts0s[tid] = tr[2] * h;
        ts1s[tid] = tr[3] * w;
        tths[tid] = tr[4];
        int lab = (int)tr[1];
        labs[tid] = lab < 0 ? 0 : (lab > 1 ? 1 : lab);
        mks[tid] = masks[b * T_ + tid];
    }
    __syncthreads();

    // ---- phase 0: thread = p ----
    if (tid < P_) {
        const int p = tid;
        float4 s4 = scal4[(size_t)b * P_ + p];
        float pth = pths[(size_t)b * P_ + p];
#pragma unroll
        for (int t = 0; t < T_; ++t) {
            float d = dist[(size_t)(b * T_ + t) * P_ + p];
            float li = liou[(size_t)(b * T_ + t) * P_ + p];
            float dsc = 1.f - d / dm + 0.01f;
            float d0 = s4.z - ts0s[t], d1 = s4.w - ts1s[t];
            float ssc = 1.f - sqrtf(d0 * d0 + d1 * d1) / sm + 0.01f;
            float tsc = 1.f - fabsf(pth - tths[t]) * 180.f / tm + 0.01f;
            float reg = fmaxf(dsc, 1e-3f) * fmaxf(ssc, 1e-3f) * fmaxf(tsc, 1e-3f);
            float c = -(reg * reg) * 3.f + (labs[t] ? s4.y : s4.x);
            if (mks[t] <= 0) c = BIGC;
            costL[t][p] = c;
            liouL[t][p] = li;
        }
    } else {
#pragma unroll
        for (int t = 0; t < T_; ++t) {
            costL[t][tid] = INFINITY;
            liouL[t][tid] = -INFINITY;
        }
    }
    __syncthreads();

    // ---- phase 1: wave = t ----
    {
        const int t = tid >> 6;
        const int lane = tid & 63;
        const int mk = mks[t];

        // sum of top-4 liou (desc order), lexicographic (val desc, idx asc)
        unsigned int deact = 0;
        float sum = 0.f;
#pragma unroll
        for (int r = 0; r < 4; ++r) {
            float bv = -INFINITY; int bi = 0x7fffffff;
#pragma unroll
            for (int i = 0; i < 16; ++i) {
                int idx = lane + 64 * i;
                float v = liouL[t][idx];
                if (deact & (1u << i)) v = -INFINITY;
                if (v > bv || (v == bv && idx < bi)) { bv = v; bi = idx; }
            }
            for (int off = 32; off; off >>= 1) {
                float ov = __shfl_xor(bv, off, 64);
                int oi = __shfl_xor(bi, off, 64);
                if (ov > bv || (ov == bv && oi < bi)) { bv = ov; bi = oi; }
            }
            sum += bv;
            if ((bi & 63) == lane) deact |= 1u << (bi >> 6);   // scalar mask, no array
        }
        int dk = 0;
        if (mk > 0) {
            dk = (int)sum;                 // trunc toward zero == astype(int32)
            if (dk < 1) dk = 1;
            if (dk > 4) dk = 4;
        }

        // top-4 lowest cost, tie-break lower p (lax.top_k stable semantics)
        int sp[4];
        deact = 0;
#pragma unroll
        for (int r = 0; r < 4; ++r) {
            float bv = INFINITY; int bi = 0x7fffffff;
#pragma unroll
            for (int i = 0; i < 16; ++i) {
                int idx = lane + 64 * i;
                float v = costL[t][idx];
                if (deact & (1u << i)) v = INFINITY;
                if (v < bv || (v == bv && idx < bi)) { bv = v; bi = idx; }
            }
            for (int off = 32; off; off >>= 1) {
                float ov = __shfl_xor(bv, off, 64);
                int oi = __shfl_xor(bi, off, 64);
                if (ov < bv || (ov == bv && oi < bi)) { bv = ov; bi = oi; }
            }
            sp[r] = bi;
            if ((bi & 63) == lane) deact |= 1u << (bi >> 6);
        }

        if (lane == 0) {
            selE[4 * t + 0] = (dk > 0) ? sp[0] : -1;
            selE[4 * t + 1] = (dk > 1) ? sp[1] : -1;
            selE[4 * t + 2] = (dk > 2) ? sp[2] : -1;
            selE[4 * t + 3] = (dk > 3) ? sp[3] : -1;
        }
    }
    __syncthreads();

    // ---- phase 2: conflict resolution + output (thread = p) ----
    if (tid < P_) {
        const int p = tid;
        unsigned int m = 0;
#pragma unroll
        for (int t2 = 0; t2 < T_; ++t2) {
            bool hit = (selE[4 * t2] == p) | (selE[4 * t2 + 1] == p) |
                       (selE[4 * t2 + 2] == p) | (selE[4 * t2 + 3] == p);
            if (hit) m |= 1u << t2;
        }
        int matched = -1;
        if (m) {
            if (__popc(m) == 1) {
                matched = __ffs(m) - 1;
            } else {
                float best = INFINITY;
#pragma unroll
                for (int t2 = 0; t2 < T_; ++t2) {
                    if ((m >> t2) & 1u) {
                        float c = costL[t2][p];
                        if (c < best) { best = c; matched = t2; }  // strict <: first-min
                    }
                }
            }
        }
        out[b * P_ + p] = (matched >= 0) ? 1 : 0;
        out[B_ * P_ + b * P_ + p] = matched;
    }
}

extern "C" void kernel_launch(void* const* d_in, const int* in_sizes, int n_in,
                              void* d_out, int out_size, void* d_ws, size_t ws_size,
                              hipStream_t stream) {
    const float* preds   = (const float*)d_in[0];
    const float* targets = (const float*)d_in[1];
    const int*   masks   = (const int*)d_in[2];
    const int*   imgw    = (const int*)d_in[3];
    const int*   imgh    = (const int*)d_in[4];
    int* out = (int*)d_out;

    char* ws = (char*)d_ws;
    const size_t SZ = (size_t)B_ * T_ * P_ * sizeof(float);     // 2,048,000 B
    float*  dist  = (float*)ws;                                  // [B][T][P]
    float*  liou  = (float*)(ws + SZ);                           // [B][T][P]
    float4* scal4 = (float4*)(ws + 2 * SZ);                      // [B][P] {fc0,fc1,ps0,ps1}
    float*  pths  = (float*)(ws + 2 * SZ + (size_t)B_ * P_ * 16);// [B][P]
    float*  pmax  = (float*)(ws + 2 * SZ + (size_t)B_ * P_ * 20);// [B][NXB][3]

    k1<<<dim3(NXB, B_), 1024, 0, stream>>>(preds, targets, imgw, imgh, dist, liou, scal4, pths, pmax);
    k2<<<B_, 1024, 0, stream>>>(targets, masks, imgw, imgh, dist, liou, scal4, pths, pmax, out);
}

// Round 9
// 38.713 us; speedup vs baseline: 1.1043x; 1.1043x over previous
//
#include <hip/hip_runtime.h>
#include <math.h>

#define B_ 32
#define P_ 1000
#define T_ 16
#define D_ 78
#define O_ 72
#define NXB 16            // p-chunks of 64
#define BIGC 100000000.0f

// ---------------- K1: dist & liou + per-p scalars + per-block partial maxes ----------------
// (unchanged since round 7 — verified outputs)
__global__ __launch_bounds__(1024, 8) void k1(
        const float* __restrict__ preds, const float* __restrict__ targets,
        const int* __restrict__ imgw_p, const int* __restrict__ imgh_p,
        float* __restrict__ dist, float* __restrict__ liou,
        float4* __restrict__ scal4, float* __restrict__ pths,
        float* __restrict__ pmax) {
    __shared__ float pred_s[64 * 81];
    __shared__ float2 tomg[T_ * O_];
    __shared__ float Spart[T_][4][64];
    __shared__ float wmax[16][3];
    __shared__ float cnt_s[T_], clen_s[T_], ts0_s[T_], ts1_s[T_], tth_s[T_];

    const int b = blockIdx.y, bx = blockIdx.x;
    const int p0 = bx * 64;
    const int rows = min(64, P_ - p0);
    const int tid = threadIdx.x;
    const float w = (float)(imgw_p[0] - 1);
    const float h = (float)(imgh_p[0] - 1);
    const float imgwf = (float)imgw_p[0];

    {
        const float4* gbase = (const float4*)(preds + ((size_t)b * P_ + p0) * D_);
        const int n4 = rows * D_ / 4;
        for (int i = tid; i < n4; i += 1024) {
            float4 v = gbase[i];
            int base = i * 4;
            int r = base / D_, c = base - r * D_;
#pragma unroll
            for (int k = 0; k < 4; ++k) {
                int cc = c + k, rr = r;
                if (cc >= D_) { cc -= D_; ++rr; }
                float x = (&v.x)[k];
                if (cc >= 6 || cc == 3) x *= w;
                pred_s[rr * 81 + cc] = x;
            }
        }
    }
    for (int i = tid; i < T_ * O_; i += 1024) {
        int t = i / O_, o = i - t * O_;
        float to = targets[((size_t)b * T_ + t) * D_ + 6 + o] * w;
        float m = (to >= 0.f && to < imgwf) ? 1.f : 0.f;
        tomg[((t >> 2) * O_ + o) * 4 + (t & 3)] = make_float2(to, m);
    }
    __syncthreads();
    if (tid < T_) {
        int t = tid;
        float c = 0.f;
        for (int o = 0; o < O_; ++o) c += tomg[((t >> 2) * O_ + o) * 4 + (t & 3)].y;
        cnt_s[t] = c;
        clen_s[t] = fmaxf(c, 1.f);
        const float* tr = targets + ((size_t)b * T_ + t) * D_;
        ts0_s[t] = tr[2] * h;
        ts1_s[t] = tr[3] * w;
        tth_s[t] = tr[4];
    }
    __syncthreads();

    {
        const int lane = tid & 63;
        const int wv = tid >> 6;
        const int tg = wv & 3;
        const int oq = wv >> 2;
        const float* lrow = pred_s + lane * 81;
        const float4* tg4 = (const float4*)(tomg + (size_t)tg * O_ * 4);
        const int o_lo = oq * 18;
        float S0 = 0.f, S1 = 0.f, S2 = 0.f, S3 = 0.f;
#pragma unroll
        for (int i = 0; i < 18; ++i) {
            int o = o_lo + i;
            float po = lrow[6 + o];
            float4 r0 = tg4[2 * o];
            float4 r1 = tg4[2 * o + 1];
            S0 += r0.y * fabsf(po - r0.x);
            S1 += r0.w * fabsf(po - r0.z);
            S2 += r1.y * fabsf(po - r1.x);
            S3 += r1.w * fabsf(po - r1.z);
        }
        Spart[4 * tg + 0][oq][lane] = S0;
        Spart[4 * tg + 1][oq][lane] = S1;
        Spart[4 * tg + 2][oq][lane] = S2;
        Spart[4 * tg + 3][oq][lane] = S3;
    }
    __syncthreads();

    const int th = tid >> 6, pl = tid & 63;
    const int p = p0 + pl;
    float ldm = 0.f, lsm = 0.f, ltm = 0.f;
    if (pl < rows) {
        float S = ((Spart[th][0][pl] + Spart[th][1][pl]) + Spart[th][2][pl]) + Spart[th][3][pl];
        float dv = S / clen_s[th];
        dist[(size_t)(b * T_ + th) * P_ + p] = dv;
        ldm = dv;
        float c30 = 30.f * cnt_s[th];
        liou[(size_t)(b * T_ + th) * P_ + p] = (c30 - S) / (c30 + S + 1e-9f);
        const float* prow = pred_s + pl * 81;
        float ps0 = prow[2] * h, ps1 = prow[3], pth = prow[4];
        float d0 = ps0 - ts0_s[th], d1 = ps1 - ts1_s[th];
        lsm = sqrtf(d0 * d0 + d1 * d1);
        ltm = fabsf(pth - tth_s[th]) * 180.f;
        if (th == 0) {
            float fc[2];
#pragma unroll
            for (int c = 0; c < 2; ++c) {
                float x = prow[c];
                float pc = 1.f / (1.f + expf(-x));
                float neg = -logf(1.f - pc + 1e-12f) * 0.75f * pc * pc;
                float pos = -logf(pc + 1e-12f) * 0.25f * (1.f - pc) * (1.f - pc);
                fc[c] = pos - neg;
            }
            scal4[(size_t)b * P_ + p] = make_float4(fc[0], fc[1], ps0, ps1);
            pths[(size_t)b * P_ + p] = pth;
        }
    }

    for (int off = 32; off; off >>= 1) {
        ldm = fmaxf(ldm, __shfl_xor(ldm, off, 64));
        lsm = fmaxf(lsm, __shfl_xor(lsm, off, 64));
        ltm = fmaxf(ltm, __shfl_xor(ltm, off, 64));
    }
    if (pl == 0) { wmax[th][0] = ldm; wmax[th][1] = lsm; wmax[th][2] = ltm; }
    __syncthreads();
    if (tid == 0) {
        float m0 = 0.f, m1 = 0.f, m2 = 0.f;
#pragma unroll
        for (int i = 0; i < 16; ++i) {
            m0 = fmaxf(m0, wmax[i][0]);
            m1 = fmaxf(m1, wmax[i][1]);
            m2 = fmaxf(m2, wmax[i][2]);
        }
        float* q = pmax + (size_t)(b * NXB + bx) * 3;
        q[0] = m0; q[1] = m1; q[2] = m2;
    }
}

// ---------------- K2: one single-wave block per (b,t) — cost + dynamic-k + top-4 ----------------
// All per-lane state in NAMED scalars (L0..L15, C0..C15) via macros: no indexable
// object exists, so nothing can be demoted to scratch (rule #20). 512 blocks spread
// the 512 tasks across all CUs (round-8's 32-block version starved on 32 CUs).
#define FOREACH16(M) M(0) M(1) M(2) M(3) M(4) M(5) M(6) M(7) \
                     M(8) M(9) M(10) M(11) M(12) M(13) M(14) M(15)

__global__ __launch_bounds__(64) void k2(
        const float* __restrict__ targets, const int* __restrict__ masks,
        const int* __restrict__ imgw_p, const int* __restrict__ imgh_p,
        const float* __restrict__ dist, const float* __restrict__ liou,
        const float4* __restrict__ scal4, const float* __restrict__ pths,
        const float* __restrict__ pmax,
        float* __restrict__ cost, int4* __restrict__ sel) {
    const int wid = blockIdx.x;              // (b,t)
    const int b = wid >> 4, t = wid & 15;
    const int lane = threadIdx.x;

    // per-batch maxes from the 16 partials (wave-uniform scalar loads)
    float dm = 0.f, sm = 0.f, tm = 0.f;
    for (int i = 0; i < NXB; ++i) {
        const float* q = pmax + (size_t)(b * NXB + i) * 3;
        dm = fmaxf(dm, q[0]); sm = fmaxf(sm, q[1]); tm = fmaxf(tm, q[2]);
    }
    dm = fmaxf(dm, 1e-8f); sm = fmaxf(sm, 1e-8f); tm = fmaxf(tm, 1e-8f);

    const float w = (float)(imgw_p[0] - 1);
    const float h = (float)(imgh_p[0] - 1);
    const float* tr = targets + (size_t)(b * T_ + t) * D_;
    const float ts0 = tr[2] * h, ts1 = tr[3] * w, tth = tr[4];
    int lab = (int)tr[1]; lab = lab < 0 ? 0 : (lab > 1 ? 1 : lab);
    const int mk = masks[b * T_ + t];

    const float* drow = dist + (size_t)(b * T_ + t) * P_;
    const float* lrow = liou + (size_t)(b * T_ + t) * P_;
    float* crow = cost + (size_t)(b * T_ + t) * P_;
    const float4* s4b = scal4 + (size_t)b * P_;
    const float* ptb = pths + (size_t)b * P_;

#define DECL(i) float L##i, C##i;
    FOREACH16(DECL)
#undef DECL

#define CHUNK(i) {                                                        \
        int p = lane + 64 * (i);                                          \
        if (p < P_) {                                                     \
            float d = drow[p];                                            \
            float4 s4 = s4b[p];                                           \
            float pth = ptb[p];                                           \
            float dsc = 1.f - d / dm + 0.01f;                             \
            float d0 = s4.z - ts0, d1 = s4.w - ts1;                       \
            float ssc = 1.f - sqrtf(d0 * d0 + d1 * d1) / sm + 0.01f;      \
            float tsc = 1.f - fabsf(pth - tth) * 180.f / tm + 0.01f;      \
            float reg = fmaxf(dsc, 1e-3f) * fmaxf(ssc, 1e-3f) * fmaxf(tsc, 1e-3f); \
            float c = -(reg * reg) * 3.f + (lab ? s4.y : s4.x);           \
            if (mk <= 0) c = BIGC;                                        \
            crow[p] = c;                                                  \
            C##i = c;                                                     \
            L##i = lrow[p];                                               \
        } else {                                                          \
            C##i = INFINITY;                                              \
            L##i = -INFINITY;                                             \
        } }
    FOREACH16(CHUNK)
#undef CHUNK

    unsigned int deact;
    float bv; int bi;

#define SCANMAX(i) { float v = (deact & (1u << (i))) ? -INFINITY : L##i;  \
        int ix = lane + 64 * (i);                                         \
        if (v > bv || (v == bv && ix < bi)) { bv = v; bi = ix; } }
#define SCANMIN(i) { float v = (deact & (1u << (i))) ? INFINITY : C##i;   \
        int ix = lane + 64 * (i);                                         \
        if (v < bv || (v == bv && ix < bi)) { bv = v; bi = ix; } }
#define BFLYMAX for (int off = 32; off; off >>= 1) {                      \
        float ov = __shfl_xor(bv, off, 64);                               \
        int oi = __shfl_xor(bi, off, 64);                                 \
        if (ov > bv || (ov == bv && oi < bi)) { bv = ov; bi = oi; } }
#define BFLYMIN for (int off = 32; off; off >>= 1) {                      \
        float ov = __shfl_xor(bv, off, 64);                               \
        int oi = __shfl_xor(bi, off, 64);                                 \
        if (ov < bv || (ov == bv && oi < bi)) { bv = ov; bi = oi; } }
#define DEACT if ((bi & 63) == lane) deact |= 1u << (bi >> 6);

    // ---- sum of top-4 liou (desc order) ----
    float sum = 0.f;
    deact = 0;
#define ROUNDMAX { bv = -INFINITY; bi = 0x7fffffff;                       \
        FOREACH16(SCANMAX) BFLYMAX sum += bv; DEACT }
    ROUNDMAX ROUNDMAX ROUNDMAX ROUNDMAX
#undef ROUNDMAX

    int dk = 0;
    if (mk > 0) {
        dk = (int)sum;                // trunc toward zero == astype(int32)
        if (dk < 1) dk = 1;
        if (dk > 4) dk = 4;
    }

    // ---- top-4 lowest cost (asc, lower-p tie-break) ----
    int s0, s1, s2, s3;
    deact = 0;
#define ROUNDMIN(sr) { bv = INFINITY; bi = 0x7fffffff;                    \
        FOREACH16(SCANMIN) BFLYMIN sr = bi; DEACT }
    ROUNDMIN(s0) ROUNDMIN(s1) ROUNDMIN(s2) ROUNDMIN(s3)
#undef ROUNDMIN

    if (lane == 0) {
        sel[wid] = make_int4(dk > 0 ? s0 : -1, dk > 1 ? s1 : -1,
                             dk > 2 ? s2 : -1, dk > 3 ? s3 : -1);
    }
#undef SCANMAX
#undef SCANMIN
#undef BFLYMAX
#undef BFLYMIN
#undef DEACT
}

// ---------------- K3: membership + conflict resolution + output ----------------
__global__ __launch_bounds__(256) void k3(const int4* __restrict__ sel,
                                          const float* __restrict__ cost,
                                          int* __restrict__ out) {
    __shared__ int selE[64];
    const int b = blockIdx.y, cx = blockIdx.x;
    if (threadIdx.x < 64) selE[threadIdx.x] = ((const int*)sel)[b * 64 + threadIdx.x];
    __syncthreads();

    const int p = cx * 250 + threadIdx.x;
    if (threadIdx.x < 250) {
        unsigned int m = 0;
#pragma unroll
        for (int t = 0; t < T_; ++t) {
            bool hit = (selE[4 * t] == p) | (selE[4 * t + 1] == p) |
                       (selE[4 * t + 2] == p) | (selE[4 * t + 3] == p);
            if (hit) m |= 1u << t;
        }
        int matched = -1;
        if (m) {
            if (__popc(m) == 1) {
                matched = __ffs(m) - 1;
            } else {
                float best = INFINITY;
#pragma unroll
                for (int t = 0; t < T_; ++t) {
                    if ((m >> t) & 1u) {
                        float c = cost[(size_t)(b * T_ + t) * P_ + p];
                        if (c < best) { best = c; matched = t; }  // strict <: first-min
                    }
                }
            }
        }
        out[b * P_ + p] = (matched >= 0) ? 1 : 0;
        out[B_ * P_ + b * P_ + p] = matched;
    }
}

extern "C" void kernel_launch(void* const* d_in, const int* in_sizes, int n_in,
                              void* d_out, int out_size, void* d_ws, size_t ws_size,
                              hipStream_t stream) {
    const float* preds   = (const float*)d_in[0];
    const float* targets = (const float*)d_in[1];
    const int*   masks   = (const int*)d_in[2];
    const int*   imgw    = (const int*)d_in[3];
    const int*   imgh    = (const int*)d_in[4];
    int* out = (int*)d_out;

    char* ws = (char*)d_ws;
    const size_t SZ = (size_t)B_ * T_ * P_ * sizeof(float);       // 2,048,000 B
    float*  dist  = (float*)ws;                                    // [B][T][P]
    float*  liou  = (float*)(ws + SZ);                             // [B][T][P]
    float*  cost  = (float*)(ws + 2 * SZ);                         // [B][T][P]
    float4* scal4 = (float4*)(ws + 3 * SZ);                        // [B][P]
    float*  pths  = (float*)(ws + 3 * SZ + (size_t)B_ * P_ * 16);  // [B][P]
    float*  pmax  = (float*)(ws + 3 * SZ + (size_t)B_ * P_ * 20);  // [B][NXB][3]
    int4*   sel   = (int4*)(ws + 3 * SZ + (size_t)B_ * P_ * 20 + (size_t)B_ * NXB * 3 * 4 + 64);

    k1<<<dim3(NXB, B_), 1024, 0, stream>>>(preds, targets, imgw, imgh, dist, liou, scal4, pths, pmax);
    k2<<<B_ * T_, 64, 0, stream>>>(targets, masks, imgw, imgh, dist, liou, scal4, pths, pmax, cost, sel);
    k3<<<dim3(4, B_), 256, 0, stream>>>(sel, cost, out);
}

// Round 10
// 38.711 us; speedup vs baseline: 1.1043x; 1.0000x over previous
//
#include <hip/hip_runtime.h>
#include <math.h>

#define B_ 32
#define P_ 1000
#define T_ 16
#define D_ 78
#define O_ 72
#define NXB 16            // p-chunks of 64
#define BIGC 100000000.0f

// ---------------- K1: dist & liou + per-p scalars + per-block partial maxes ----------------
// (unchanged since round 7 — verified outputs)
__global__ __launch_bounds__(1024, 8) void k1(
        const float* __restrict__ preds, const float* __restrict__ targets,
        const int* __restrict__ imgw_p, const int* __restrict__ imgh_p,
        float* __restrict__ dist, float* __restrict__ liou,
        float4* __restrict__ scal4, float* __restrict__ pths,
        float* __restrict__ pmax) {
    __shared__ float pred_s[64 * 81];
    __shared__ float2 tomg[T_ * O_];
    __shared__ float Spart[T_][4][64];
    __shared__ float wmax[16][3];
    __shared__ float cnt_s[T_], clen_s[T_], ts0_s[T_], ts1_s[T_], tth_s[T_];

    const int b = blockIdx.y, bx = blockIdx.x;
    const int p0 = bx * 64;
    const int rows = min(64, P_ - p0);
    const int tid = threadIdx.x;
    const float w = (float)(imgw_p[0] - 1);
    const float h = (float)(imgh_p[0] - 1);
    const float imgwf = (float)imgw_p[0];

    {
        const float4* gbase = (const float4*)(preds + ((size_t)b * P_ + p0) * D_);
        const int n4 = rows * D_ / 4;
        for (int i = tid; i < n4; i += 1024) {
            float4 v = gbase[i];
            int base = i * 4;
            int r = base / D_, c = base - r * D_;
#pragma unroll
            for (int k = 0; k < 4; ++k) {
                int cc = c + k, rr = r;
                if (cc >= D_) { cc -= D_; ++rr; }
                float x = (&v.x)[k];
                if (cc >= 6 || cc == 3) x *= w;
                pred_s[rr * 81 + cc] = x;
            }
        }
    }
    for (int i = tid; i < T_ * O_; i += 1024) {
        int t = i / O_, o = i - t * O_;
        float to = targets[((size_t)b * T_ + t) * D_ + 6 + o] * w;
        float m = (to >= 0.f && to < imgwf) ? 1.f : 0.f;
        tomg[((t >> 2) * O_ + o) * 4 + (t & 3)] = make_float2(to, m);
    }
    __syncthreads();
    if (tid < T_) {
        int t = tid;
        float c = 0.f;
        for (int o = 0; o < O_; ++o) c += tomg[((t >> 2) * O_ + o) * 4 + (t & 3)].y;
        cnt_s[t] = c;
        clen_s[t] = fmaxf(c, 1.f);
        const float* tr = targets + ((size_t)b * T_ + t) * D_;
        ts0_s[t] = tr[2] * h;
        ts1_s[t] = tr[3] * w;
        tth_s[t] = tr[4];
    }
    __syncthreads();

    {
        const int lane = tid & 63;
        const int wv = tid >> 6;
        const int tg = wv & 3;
        const int oq = wv >> 2;
        const float* lrow = pred_s + lane * 81;
        const float4* tg4 = (const float4*)(tomg + (size_t)tg * O_ * 4);
        const int o_lo = oq * 18;
        float S0 = 0.f, S1 = 0.f, S2 = 0.f, S3 = 0.f;
#pragma unroll
        for (int i = 0; i < 18; ++i) {
            int o = o_lo + i;
            float po = lrow[6 + o];
            float4 r0 = tg4[2 * o];
            float4 r1 = tg4[2 * o + 1];
            S0 += r0.y * fabsf(po - r0.x);
            S1 += r0.w * fabsf(po - r0.z);
            S2 += r1.y * fabsf(po - r1.x);
            S3 += r1.w * fabsf(po - r1.z);
        }
        Spart[4 * tg + 0][oq][lane] = S0;
        Spart[4 * tg + 1][oq][lane] = S1;
        Spart[4 * tg + 2][oq][lane] = S2;
        Spart[4 * tg + 3][oq][lane] = S3;
    }
    __syncthreads();

    const int th = tid >> 6, pl = tid & 63;
    const int p = p0 + pl;
    float ldm = 0.f, lsm = 0.f, ltm = 0.f;
    if (pl < rows) {
        float S = ((Spart[th][0][pl] + Spart[th][1][pl]) + Spart[th][2][pl]) + Spart[th][3][pl];
        float dv = S / clen_s[th];
        dist[(size_t)(b * T_ + th) * P_ + p] = dv;
        ldm = dv;
        float c30 = 30.f * cnt_s[th];
        liou[(size_t)(b * T_ + th) * P_ + p] = (c30 - S) / (c30 + S + 1e-9f);
        const float* prow = pred_s + pl * 81;
        float ps0 = prow[2] * h, ps1 = prow[3], pth = prow[4];
        float d0 = ps0 - ts0_s[th], d1 = ps1 - ts1_s[th];
        lsm = sqrtf(d0 * d0 + d1 * d1);
        ltm = fabsf(pth - tth_s[th]) * 180.f;
        if (th == 0) {
            float fc[2];
#pragma unroll
            for (int c = 0; c < 2; ++c) {
                float x = prow[c];
                float pc = 1.f / (1.f + expf(-x));
                float neg = -logf(1.f - pc + 1e-12f) * 0.75f * pc * pc;
                float pos = -logf(pc + 1e-12f) * 0.25f * (1.f - pc) * (1.f - pc);
                fc[c] = pos - neg;
            }
            scal4[(size_t)b * P_ + p] = make_float4(fc[0], fc[1], ps0, ps1);
            pths[(size_t)b * P_ + p] = pth;
        }
    }

    for (int off = 32; off; off >>= 1) {
        ldm = fmaxf(ldm, __shfl_xor(ldm, off, 64));
        lsm = fmaxf(lsm, __shfl_xor(lsm, off, 64));
        ltm = fmaxf(ltm, __shfl_xor(ltm, off, 64));
    }
    if (pl == 0) { wmax[th][0] = ldm; wmax[th][1] = lsm; wmax[th][2] = ltm; }
    __syncthreads();
    if (tid == 0) {
        float m0 = 0.f, m1 = 0.f, m2 = 0.f;
#pragma unroll
        for (int i = 0; i < 16; ++i) {
            m0 = fmaxf(m0, wmax[i][0]);
            m1 = fmaxf(m1, wmax[i][1]);
            m2 = fmaxf(m2, wmax[i][2]);
        }
        float* q = pmax + (size_t)(b * NXB + bx) * 3;
        q[0] = m0; q[1] = m1; q[2] = m2;
    }
}

// ---------------- K2: one single-wave block per (b,t) — cost + dynamic-k + top-4 ----------------
// Named scalars (no indexable object) AND __launch_bounds__(64, 1): min 1 wave/EU
// gives the full VGPR budget so the 32 L/C values live in registers.
// (Round 9's VGPR_Count=32 proved the default occupancy target was forcing a
// 32-VGPR cap -> spill/reload on every scan round.)
#define FOREACH16(M) M(0) M(1) M(2) M(3) M(4) M(5) M(6) M(7) \
                     M(8) M(9) M(10) M(11) M(12) M(13) M(14) M(15)

__global__ __launch_bounds__(64, 1) void k2(
        const float* __restrict__ targets, const int* __restrict__ masks,
        const int* __restrict__ imgw_p, const int* __restrict__ imgh_p,
        const float* __restrict__ dist, const float* __restrict__ liou,
        const float4* __restrict__ scal4, const float* __restrict__ pths,
        const float* __restrict__ pmax,
        float* __restrict__ cost, int4* __restrict__ sel) {
    const int wid = blockIdx.x;              // (b,t)
    const int b = wid >> 4, t = wid & 15;
    const int lane = threadIdx.x;

    // per-batch maxes from the 16 partials (wave-uniform scalar loads)
    float dm = 0.f, sm = 0.f, tm = 0.f;
    for (int i = 0; i < NXB; ++i) {
        const float* q = pmax + (size_t)(b * NXB + i) * 3;
        dm = fmaxf(dm, q[0]); sm = fmaxf(sm, q[1]); tm = fmaxf(tm, q[2]);
    }
    dm = fmaxf(dm, 1e-8f); sm = fmaxf(sm, 1e-8f); tm = fmaxf(tm, 1e-8f);

    const float w = (float)(imgw_p[0] - 1);
    const float h = (float)(imgh_p[0] - 1);
    const float* tr = targets + (size_t)(b * T_ + t) * D_;
    const float ts0 = tr[2] * h, ts1 = tr[3] * w, tth = tr[4];
    int lab = (int)tr[1]; lab = lab < 0 ? 0 : (lab > 1 ? 1 : lab);
    const int mk = masks[b * T_ + t];

    const float* drow = dist + (size_t)(b * T_ + t) * P_;
    const float* lrow = liou + (size_t)(b * T_ + t) * P_;
    float* crow = cost + (size_t)(b * T_ + t) * P_;
    const float4* s4b = scal4 + (size_t)b * P_;
    const float* ptb = pths + (size_t)b * P_;

#define DECL(i) float L##i, C##i;
    FOREACH16(DECL)
#undef DECL

#define CHUNK(i) {                                                        \
        int p = lane + 64 * (i);                                          \
        if (p < P_) {                                                     \
            float d = drow[p];                                            \
            float4 s4 = s4b[p];                                           \
            float pth = ptb[p];                                           \
            float dsc = 1.f - d / dm + 0.01f;                             \
            float d0 = s4.z - ts0, d1 = s4.w - ts1;                       \
            float ssc = 1.f - sqrtf(d0 * d0 + d1 * d1) / sm + 0.01f;      \
            float tsc = 1.f - fabsf(pth - tth) * 180.f / tm + 0.01f;      \
            float reg = fmaxf(dsc, 1e-3f) * fmaxf(ssc, 1e-3f) * fmaxf(tsc, 1e-3f); \
            float c = -(reg * reg) * 3.f + (lab ? s4.y : s4.x);           \
            if (mk <= 0) c = BIGC;                                        \
            crow[p] = c;                                                  \
            C##i = c;                                                     \
            L##i = lrow[p];                                               \
        } else {                                                          \
            C##i = INFINITY;                                              \
            L##i = -INFINITY;                                             \
        } }
    FOREACH16(CHUNK)
#undef CHUNK

    unsigned int deact;
    float bv; int bi;

#define SCANMAX(i) { float v = (deact & (1u << (i))) ? -INFINITY : L##i;  \
        int ix = lane + 64 * (i);                                         \
        if (v > bv || (v == bv && ix < bi)) { bv = v; bi = ix; } }
#define SCANMIN(i) { float v = (deact & (1u << (i))) ? INFINITY : C##i;   \
        int ix = lane + 64 * (i);                                         \
        if (v < bv || (v == bv && ix < bi)) { bv = v; bi = ix; } }
#define BFLYMAX for (int off = 32; off; off >>= 1) {                      \
        float ov = __shfl_xor(bv, off, 64);                               \
        int oi = __shfl_xor(bi, off, 64);                                 \
        if (ov > bv || (ov == bv && oi < bi)) { bv = ov; bi = oi; } }
#define BFLYMIN for (int off = 32; off; off >>= 1) {                      \
        float ov = __shfl_xor(bv, off, 64);                               \
        int oi = __shfl_xor(bi, off, 64);                                 \
        if (ov < bv || (ov == bv && oi < bi)) { bv = ov; bi = oi; } }
#define DEACT if ((bi & 63) == lane) deact |= 1u << (bi >> 6);

    // ---- sum of top-4 liou (desc order) ----
    float sum = 0.f;
    deact = 0;
#define ROUNDMAX { bv = -INFINITY; bi = 0x7fffffff;                       \
        FOREACH16(SCANMAX) BFLYMAX sum += bv; DEACT }
    ROUNDMAX ROUNDMAX ROUNDMAX ROUNDMAX
#undef ROUNDMAX

    int dk = 0;
    if (mk > 0) {
        dk = (int)sum;                // trunc toward zero == astype(int32)
        if (dk < 1) dk = 1;
        if (dk > 4) dk = 4;
    }

    // ---- top-4 lowest cost (asc, lower-p tie-break) ----
    int s0, s1, s2, s3;
    deact = 0;
#define ROUNDMIN(sr) { bv = INFINITY; bi = 0x7fffffff;                    \
        FOREACH16(SCANMIN) BFLYMIN sr = bi; DEACT }
    ROUNDMIN(s0) ROUNDMIN(s1) ROUNDMIN(s2) ROUNDMIN(s3)
#undef ROUNDMIN

    if (lane == 0) {
        sel[wid] = make_int4(dk > 0 ? s0 : -1, dk > 1 ? s1 : -1,
                             dk > 2 ? s2 : -1, dk > 3 ? s3 : -1);
    }
#undef SCANMAX
#undef SCANMIN
#undef BFLYMAX
#undef BFLYMIN
#undef DEACT
}

// ---------------- K3: membership + conflict resolution + output ----------------
__global__ __launch_bounds__(256) void k3(const int4* __restrict__ sel,
                                          const float* __restrict__ cost,
                                          int* __restrict__ out) {
    __shared__ int selE[64];
    const int b = blockIdx.y, cx = blockIdx.x;
    if (threadIdx.x < 64) selE[threadIdx.x] = ((const int*)sel)[b * 64 + threadIdx.x];
    __syncthreads();

    const int p = cx * 250 + threadIdx.x;
    if (threadIdx.x < 250) {
        unsigned int m = 0;
#pragma unroll
        for (int t = 0; t < T_; ++t) {
            bool hit = (selE[4 * t] == p) | (selE[4 * t + 1] == p) |
                       (selE[4 * t + 2] == p) | (selE[4 * t + 3] == p);
            if (hit) m |= 1u << t;
        }
        int matched = -1;
        if (m) {
            if (__popc(m) == 1) {
                matched = __ffs(m) - 1;
            } else {
                float best = INFINITY;
#pragma unroll
                for (int t = 0; t < T_; ++t) {
                    if ((m >> t) & 1u) {
                        float c = cost[(size_t)(b * T_ + t) * P_ + p];
                        if (c < best) { best = c; matched = t; }  // strict <: first-min
                    }
                }
            }
        }
        out[b * P_ + p] = (matched >= 0) ? 1 : 0;
        out[B_ * P_ + b * P_ + p] = matched;
    }
}

extern "C" void kernel_launch(void* const* d_in, const int* in_sizes, int n_in,
                              void* d_out, int out_size, void* d_ws, size_t ws_size,
                              hipStream_t stream) {
    const float* preds   = (const float*)d_in[0];
    const float* targets = (const float*)d_in[1];
    const int*   masks   = (const int*)d_in[2];
    const int*   imgw    = (const int*)d_in[3];
    const int*   imgh    = (const int*)d_in[4];
    int* out = (int*)d_out;

    char* ws = (char*)d_ws;
    const size_t SZ = (size_t)B_ * T_ * P_ * sizeof(float);       // 2,048,000 B
    float*  dist  = (float*)ws;                                    // [B][T][P]
    float*  liou  = (float*)(ws + SZ);                             // [B][T][P]
    float*  cost  = (float*)(ws + 2 * SZ);                         // [B][T][P]
    float4* scal4 = (float4*)(ws + 3 * SZ);                        // [B][P]
    float*  pths  = (float*)(ws + 3 * SZ + (size_t)B_ * P_ * 16);  // [B][P]
    float*  pmax  = (float*)(ws + 3 * SZ + (size_t)B_ * P_ * 20);  // [B][NXB][3]
    int4*   sel   = (int4*)(ws + 3 * SZ + (size_t)B_ * P_ * 20 + (size_t)B_ * NXB * 3 * 4 + 64);

    k1<<<dim3(NXB, B_), 1024, 0, stream>>>(preds, targets, imgw, imgh, dist, liou, scal4, pths, pmax);
    k2<<<B_ * T_, 64, 0, stream>>>(targets, masks, imgw, imgh, dist, liou, scal4, pths, pmax, cost, sel);
    k3<<<dim3(4, B_), 256, 0, stream>>>(sel, cost, out);
}

// Round 11
// 34.869 us; speedup vs baseline: 1.2260x; 1.1102x over previous
//
#include <hip/hip_runtime.h>
#include <math.h>

#define B_ 32
#define P_ 1000
#define T_ 16
#define D_ 78
#define O_ 72
#define NXB 16            // p-chunks of 64
#define BIGC 100000000.0f

// ---------------- K1: dist & liou + per-p scalars + per-block partial maxes ----------------
// (unchanged since round 7 — verified outputs)
__global__ __launch_bounds__(1024, 8) void k1(
        const float* __restrict__ preds, const float* __restrict__ targets,
        const int* __restrict__ imgw_p, const int* __restrict__ imgh_p,
        float* __restrict__ dist, float* __restrict__ liou,
        float4* __restrict__ scal4, float* __restrict__ pths,
        float* __restrict__ pmax) {
    __shared__ float pred_s[64 * 81];
    __shared__ float2 tomg[T_ * O_];
    __shared__ float Spart[T_][4][64];
    __shared__ float wmax[16][3];
    __shared__ float cnt_s[T_], clen_s[T_], ts0_s[T_], ts1_s[T_], tth_s[T_];

    const int b = blockIdx.y, bx = blockIdx.x;
    const int p0 = bx * 64;
    const int rows = min(64, P_ - p0);
    const int tid = threadIdx.x;
    const float w = (float)(imgw_p[0] - 1);
    const float h = (float)(imgh_p[0] - 1);
    const float imgwf = (float)imgw_p[0];

    {
        const float4* gbase = (const float4*)(preds + ((size_t)b * P_ + p0) * D_);
        const int n4 = rows * D_ / 4;
        for (int i = tid; i < n4; i += 1024) {
            float4 v = gbase[i];
            int base = i * 4;
            int r = base / D_, c = base - r * D_;
#pragma unroll
            for (int k = 0; k < 4; ++k) {
                int cc = c + k, rr = r;
                if (cc >= D_) { cc -= D_; ++rr; }
                float x = (&v.x)[k];
                if (cc >= 6 || cc == 3) x *= w;
                pred_s[rr * 81 + cc] = x;
            }
        }
    }
    for (int i = tid; i < T_ * O_; i += 1024) {
        int t = i / O_, o = i - t * O_;
        float to = targets[((size_t)b * T_ + t) * D_ + 6 + o] * w;
        float m = (to >= 0.f && to < imgwf) ? 1.f : 0.f;
        tomg[((t >> 2) * O_ + o) * 4 + (t & 3)] = make_float2(to, m);
    }
    __syncthreads();
    if (tid < T_) {
        int t = tid;
        float c = 0.f;
        for (int o = 0; o < O_; ++o) c += tomg[((t >> 2) * O_ + o) * 4 + (t & 3)].y;
        cnt_s[t] = c;
        clen_s[t] = fmaxf(c, 1.f);
        const float* tr = targets + ((size_t)b * T_ + t) * D_;
        ts0_s[t] = tr[2] * h;
        ts1_s[t] = tr[3] * w;
        tth_s[t] = tr[4];
    }
    __syncthreads();

    {
        const int lane = tid & 63;
        const int wv = tid >> 6;
        const int tg = wv & 3;
        const int oq = wv >> 2;
        const float* lrow = pred_s + lane * 81;
        const float4* tg4 = (const float4*)(tomg + (size_t)tg * O_ * 4);
        const int o_lo = oq * 18;
        float S0 = 0.f, S1 = 0.f, S2 = 0.f, S3 = 0.f;
#pragma unroll
        for (int i = 0; i < 18; ++i) {
            int o = o_lo + i;
            float po = lrow[6 + o];
            float4 r0 = tg4[2 * o];
            float4 r1 = tg4[2 * o + 1];
            S0 += r0.y * fabsf(po - r0.x);
            S1 += r0.w * fabsf(po - r0.z);
            S2 += r1.y * fabsf(po - r1.x);
            S3 += r1.w * fabsf(po - r1.z);
        }
        Spart[4 * tg + 0][oq][lane] = S0;
        Spart[4 * tg + 1][oq][lane] = S1;
        Spart[4 * tg + 2][oq][lane] = S2;
        Spart[4 * tg + 3][oq][lane] = S3;
    }
    __syncthreads();

    const int th = tid >> 6, pl = tid & 63;
    const int p = p0 + pl;
    float ldm = 0.f, lsm = 0.f, ltm = 0.f;
    if (pl < rows) {
        float S = ((Spart[th][0][pl] + Spart[th][1][pl]) + Spart[th][2][pl]) + Spart[th][3][pl];
        float dv = S / clen_s[th];
        dist[(size_t)(b * T_ + th) * P_ + p] = dv;
        ldm = dv;
        float c30 = 30.f * cnt_s[th];
        liou[(size_t)(b * T_ + th) * P_ + p] = (c30 - S) / (c30 + S + 1e-9f);
        const float* prow = pred_s + pl * 81;
        float ps0 = prow[2] * h, ps1 = prow[3], pth = prow[4];
        float d0 = ps0 - ts0_s[th], d1 = ps1 - ts1_s[th];
        lsm = sqrtf(d0 * d0 + d1 * d1);
        ltm = fabsf(pth - tth_s[th]) * 180.f;
        if (th == 0) {
            float fc[2];
#pragma unroll
            for (int c = 0; c < 2; ++c) {
                float x = prow[c];
                float pc = 1.f / (1.f + expf(-x));
                float neg = -logf(1.f - pc + 1e-12f) * 0.75f * pc * pc;
                float pos = -logf(pc + 1e-12f) * 0.25f * (1.f - pc) * (1.f - pc);
                fc[c] = pos - neg;
            }
            scal4[(size_t)b * P_ + p] = make_float4(fc[0], fc[1], ps0, ps1);
            pths[(size_t)b * P_ + p] = pth;
        }
    }

    for (int off = 32; off; off >>= 1) {
        ldm = fmaxf(ldm, __shfl_xor(ldm, off, 64));
        lsm = fmaxf(lsm, __shfl_xor(lsm, off, 64));
        ltm = fmaxf(ltm, __shfl_xor(ltm, off, 64));
    }
    if (pl == 0) { wmax[th][0] = ldm; wmax[th][1] = lsm; wmax[th][2] = ltm; }
    __syncthreads();
    if (tid == 0) {
        float m0 = 0.f, m1 = 0.f, m2 = 0.f;
#pragma unroll
        for (int i = 0; i < 16; ++i) {
            m0 = fmaxf(m0, wmax[i][0]);
            m1 = fmaxf(m1, wmax[i][1]);
            m2 = fmaxf(m2, wmax[i][2]);
        }
        float* q = pmax + (size_t)(b * NXB + bx) * 3;
        q[0] = m0; q[1] = m1; q[2] = m2;
    }
}

// ---------------- K2: block per (b,t) — cost to LDS, wave-0 LDS-scan top-4 ----------------
// Scan state lives EXPLICITLY in LDS (costL/liouL); deactivation writes the
// sentinel back to LDS. No register arrays and nothing the register allocator
// can rematerialize via global reloads (the round-10 pathology: VGPR=32,
// L/C reloaded from global every round). Outputs only sel + selcost (16 KB),
// not the 2 MB cost matrix.
__global__ __launch_bounds__(256) void k2(
        const float* __restrict__ targets, const int* __restrict__ masks,
        const int* __restrict__ imgw_p, const int* __restrict__ imgh_p,
        const float* __restrict__ dist, const float* __restrict__ liou,
        const float4* __restrict__ scal4, const float* __restrict__ pths,
        const float* __restrict__ pmax,
        int4* __restrict__ sel, float4* __restrict__ selc) {
    __shared__ float costL[1024];
    __shared__ float liouL[1024];

    const int wid = blockIdx.x;              // (b,t)
    const int b = wid >> 4, t = wid & 15;
    const int tid = threadIdx.x;

    // per-batch maxes from the 16 partials (uniform scalar loads)
    float dm = 0.f, sm = 0.f, tm = 0.f;
    for (int i = 0; i < NXB; ++i) {
        const float* q = pmax + (size_t)(b * NXB + i) * 3;
        dm = fmaxf(dm, q[0]); sm = fmaxf(sm, q[1]); tm = fmaxf(tm, q[2]);
    }
    dm = fmaxf(dm, 1e-8f); sm = fmaxf(sm, 1e-8f); tm = fmaxf(tm, 1e-8f);

    const float w = (float)(imgw_p[0] - 1);
    const float h = (float)(imgh_p[0] - 1);
    const float* tr = targets + (size_t)(b * T_ + t) * D_;
    const float ts0 = tr[2] * h, ts1 = tr[3] * w, tth = tr[4];
    int lab = (int)tr[1]; lab = lab < 0 ? 0 : (lab > 1 ? 1 : lab);
    const int mk = masks[b * T_ + t];

    const float* drow = dist + (size_t)(b * T_ + t) * P_;
    const float* lrow = liou + (size_t)(b * T_ + t) * P_;
    const float4* s4b = scal4 + (size_t)b * P_;
    const float* ptb = pths + (size_t)b * P_;

    // ---- phase 0: compute cost -> LDS (256 threads, 4 p's each, coalesced) ----
#pragma unroll
    for (int i = 0; i < 4; ++i) {
        int p = tid + 256 * i;
        if (p < P_) {
            float d = drow[p];
            float4 s4 = s4b[p];
            float pth = ptb[p];
            float dsc = 1.f - d / dm + 0.01f;
            float d0 = s4.z - ts0, d1 = s4.w - ts1;
            float ssc = 1.f - sqrtf(d0 * d0 + d1 * d1) / sm + 0.01f;
            float tsc = 1.f - fabsf(pth - tth) * 180.f / tm + 0.01f;
            float reg = fmaxf(dsc, 1e-3f) * fmaxf(ssc, 1e-3f) * fmaxf(tsc, 1e-3f);
            float c = -(reg * reg) * 3.f + (lab ? s4.y : s4.x);
            if (mk <= 0) c = BIGC;
            costL[p] = c;
            liouL[p] = lrow[p];
        } else {
            costL[p] = INFINITY;
            liouL[p] = -INFINITY;
        }
    }
    __syncthreads();
    if (tid >= 64) return;                   // wave 0 finishes alone

    const int lane = tid;

    // ---- top-4 liou (desc, lower-p tie-break), LDS rescan + LDS deactivate ----
    float sum = 0.f;
    for (int r = 0; r < 4; ++r) {
        float bv = -INFINITY; int bi = 0x7fffffff;
#pragma unroll
        for (int i = 0; i < 16; ++i) {
            int ix = lane + 64 * i;
            float v = liouL[ix];
            if (v > bv || (v == bv && ix < bi)) { bv = v; bi = ix; }
        }
        for (int off = 32; off; off >>= 1) {
            float ov = __shfl_xor(bv, off, 64);
            int oi = __shfl_xor(bi, off, 64);
            if (ov > bv || (ov == bv && oi < bi)) { bv = ov; bi = oi; }
        }
        sum += bv;
        if ((bi & 63) == lane) liouL[bi] = -INFINITY;   // same-wave LDS: in-order
    }
    int dk = 0;
    if (mk > 0) {
        dk = (int)sum;                // trunc toward zero == astype(int32)
        if (dk < 1) dk = 1;
        if (dk > 4) dk = 4;
    }

    // ---- top-4 lowest cost (asc, lower-p tie-break) ----
    int s0, s1, s2, s3;
    float c0, c1, c2, c3;
#define ROUNDMIN(sr, cr) {                                                \
        float bv = INFINITY; int bi = 0x7fffffff;                         \
        _Pragma("unroll")                                                 \
        for (int i = 0; i < 16; ++i) {                                    \
            int ix = lane + 64 * i;                                       \
            float v = costL[ix];                                          \
            if (v < bv || (v == bv && ix < bi)) { bv = v; bi = ix; }      \
        }                                                                 \
        for (int off = 32; off; off >>= 1) {                              \
            float ov = __shfl_xor(bv, off, 64);                           \
            int oi = __shfl_xor(bi, off, 64);                             \
            if (ov < bv || (ov == bv && oi < bi)) { bv = ov; bi = oi; }   \
        }                                                                 \
        sr = bi; cr = bv;                                                 \
        if ((bi & 63) == lane) costL[bi] = INFINITY; }
    ROUNDMIN(s0, c0) ROUNDMIN(s1, c1) ROUNDMIN(s2, c2) ROUNDMIN(s3, c3)
#undef ROUNDMIN

    if (lane == 0) {
        sel[wid]  = make_int4(dk > 0 ? s0 : -1, dk > 1 ? s1 : -1,
                              dk > 2 ? s2 : -1, dk > 3 ? s3 : -1);
        selc[wid] = make_float4(c0, c1, c2, c3);
    }
}

// ---------------- K3: membership + conflict resolution from sel/selc only ----------------
__global__ __launch_bounds__(256) void k3(const int* __restrict__ sel,
                                          const float* __restrict__ selc,
                                          int* __restrict__ out) {
    __shared__ int selE[64];
    __shared__ float selC[64];
    const int b = blockIdx.y, cx = blockIdx.x;
    if (threadIdx.x < 64) {
        selE[threadIdx.x] = sel[b * 64 + threadIdx.x];
        selC[threadIdx.x] = selc[b * 64 + threadIdx.x];
    }
    __syncthreads();

    const int p = cx * 250 + threadIdx.x;
    if (threadIdx.x < 250) {
        int matched = -1;
        float best = INFINITY;
#pragma unroll
        for (int t = 0; t < T_; ++t) {
#pragma unroll
            for (int j = 0; j < 4; ++j) {
                if (selE[4 * t + j] == p) {
                    float c = selC[4 * t + j];
                    if (c < best) { best = c; matched = t; }  // strict <: first-min on t
                }
            }
        }
        out[b * P_ + p] = (matched >= 0) ? 1 : 0;
        out[B_ * P_ + b * P_ + p] = matched;
    }
}

extern "C" void kernel_launch(void* const* d_in, const int* in_sizes, int n_in,
                              void* d_out, int out_size, void* d_ws, size_t ws_size,
                              hipStream_t stream) {
    const float* preds   = (const float*)d_in[0];
    const float* targets = (const float*)d_in[1];
    const int*   masks   = (const int*)d_in[2];
    const int*   imgw    = (const int*)d_in[3];
    const int*   imgh    = (const int*)d_in[4];
    int* out = (int*)d_out;

    char* ws = (char*)d_ws;
    const size_t SZ = (size_t)B_ * T_ * P_ * sizeof(float);       // 2,048,000 B
    float*  dist  = (float*)ws;                                    // [B][T][P]
    float*  liou  = (float*)(ws + SZ);                             // [B][T][P]
    float4* scal4 = (float4*)(ws + 2 * SZ);                        // [B][P] {fc0,fc1,ps0,ps1}
    float*  pths  = (float*)(ws + 2 * SZ + (size_t)B_ * P_ * 16);  // [B][P]
    float*  pmax  = (float*)(ws + 2 * SZ + (size_t)B_ * P_ * 20);  // [B][NXB][3]
    int4*   sel   = (int4*)(ws + 2 * SZ + (size_t)B_ * P_ * 20 + 8192);   // 512 * int4
    float4* selc  = (float4*)(ws + 2 * SZ + (size_t)B_ * P_ * 20 + 16384);// 512 * float4

    k1<<<dim3(NXB, B_), 1024, 0, stream>>>(preds, targets, imgw, imgh, dist, liou, scal4, pths, pmax);
    k2<<<B_ * T_, 256, 0, stream>>>(targets, masks, imgw, imgh, dist, liou, scal4, pths, pmax, sel, selc);
    k3<<<dim3(4, B_), 256, 0, stream>>>((const int*)sel, (const float*)selc, out);
}